// Round 17
// baseline (396.872 us; speedup 1.0000x reference)
//
#include <hip/hip_runtime.h>
#include <hip/hip_fp16.h>

#define NB 2048
#define NT 60
#define NDL 100
#define ND 512
#define NH 256
#define NG 768

typedef const float* __restrict__ fpp;
typedef _Float16 half8 __attribute__((ext_vector_type(8)));
typedef float floatx4 __attribute__((ext_vector_type(4)));

__device__ __forceinline__ float fast_rcp(float x) {
  return __builtin_amdgcn_rcpf(x);
}
__device__ __forceinline__ float fast_sig(float x) {
  return fast_rcp(1.f + __expf(-x));
}
__device__ __forceinline__ float fast_tanh(float x) {
  float t = __expf(2.f * x);
  return (t - 1.f) * fast_rcp(t + 1.f);
}

// ---------------------------------------------------------------------------
// fp32 tiled GEMM (fc layer, K=100) WITH FUSED BN PARTIAL SUMS:
// C = A*B^T + bias; also accumulates per-column sum / sumsq into s1g/s2g
// via LDS reduction + one atomicAdd per column per block.
// ---------------------------------------------------------------------------
__global__ __launch_bounds__(256) void gemm_fc_bn(
    fpp A, fpp Bm, fpp bias, float* __restrict__ C,
    float* __restrict__ s1g, float* __restrict__ s2g,
    int M, int N, int K, int lda, int ldb, int ldc)
{
  __shared__ float As[16][68];
  __shared__ float Bs[16][68];
  __shared__ float red1[16][64];
  __shared__ float red2[16][64];
  const int bm = blockIdx.x * 64, bn = blockIdx.y * 64;
  const int tid = threadIdx.x;
  const int tx = tid & 15, ty = tid >> 4;
  float acc[4][4] = {};
  for (int k0 = 0; k0 < K; k0 += 16) {
#pragma unroll
    for (int i = 0; i < 4; i++) {
      int e = tid + i * 256;
      int m = e >> 4, k = e & 15;
      As[k][m] = (k0 + k < K) ? A[(size_t)(bm + m) * lda + k0 + k] : 0.f;
      Bs[k][m] = (k0 + k < K) ? Bm[(size_t)(bn + m) * ldb + k0 + k] : 0.f;
    }
    __syncthreads();
#pragma unroll
    for (int kk = 0; kk < 16; kk++) {
      float4 av = *(const float4*)&As[kk][ty * 4];
      float4 bv = *(const float4*)&Bs[kk][tx * 4];
      float a_[4] = {av.x, av.y, av.z, av.w};
      float b_[4] = {bv.x, bv.y, bv.z, bv.w};
#pragma unroll
      for (int i = 0; i < 4; i++)
#pragma unroll
        for (int j = 0; j < 4; j++)
          acc[i][j] = fmaf(a_[i], b_[j], acc[i][j]);
    }
    __syncthreads();
  }
#pragma unroll
  for (int j = 0; j < 4; j++) {
    int n = bn + tx * 4 + j;
    float bv = bias[n];
    float s1 = 0.f, s2 = 0.f;
#pragma unroll
    for (int i = 0; i < 4; i++) {
      int m = bm + ty * 4 + i;
      float v = acc[i][j] + bv;
      C[(size_t)m * ldc + n] = v;
      s1 += v; s2 += v * v;
    }
    red1[ty][tx * 4 + j] = s1;
    red2[ty][tx * 4 + j] = s2;
  }
  __syncthreads();
  if (tid < 64) {
    float s1 = 0.f, s2 = 0.f;
#pragma unroll
    for (int r = 0; r < 16; r++) { s1 += red1[r][tid]; s2 += red2[r][tid]; }
    atomicAdd(&s1g[bn + tid], s1);
    atomicAdd(&s2g[bn + tid], s2);
  }
}

// bn (stats from s1/s2) + leaky relu, writing fp16
__global__ void bn_lrelu_h16(const float* __restrict__ h0,
                             fpp g, fpp b,
                             const float* __restrict__ s1g,
                             const float* __restrict__ s2g,
                             __half* __restrict__ h16g)
{
  int idx = blockIdx.x * 256 + threadIdx.x;
  int d = idx & (ND - 1);
  float mu = s1g[d] * (1.f / NB);
  float var = s2g[d] * (1.f / NB) - mu * mu;
  float sc = g[d] * rsqrtf(var + 1e-5f);
  float sh = b[d] - mu * sc;
  float v = h0[idx] * sc + sh;
  h16g[idx] = __float2half(v >= 0.f ? v : 0.2f * v);
}

// ---------------------------------------------------------------------------
// One-time weight conversions fp32 -> fp16 (+ zero-padded jW 16x512)
// ---------------------------------------------------------------------------
__global__ void convert_w(fpp whf, fpp whb, fpp w1, fpp wif, fpp wib, fpp jw,
                          __half* __restrict__ o_whf, __half* __restrict__ o_whb,
                          __half* __restrict__ o_w1, __half* __restrict__ o_wif,
                          __half* __restrict__ o_wib, __half* __restrict__ o_jw)
{
  int idx = blockIdx.x * 256 + threadIdx.x;  // 0 .. 1318911
  if (idx < 196608) o_whf[idx] = __float2half(whf[idx]);
  else if (idx < 393216) o_whb[idx - 196608] = __float2half(whb[idx - 196608]);
  else if (idx < 524288) o_w1[idx - 393216] = __float2half(w1[idx - 393216]);
  else if (idx < 917504) o_wif[idx - 524288] = __float2half(wif[idx - 524288]);
  else if (idx < 1310720) o_wib[idx - 917504] = __float2half(wib[idx - 917504]);
  else if (idx < 1318912) {
    int e = idx - 1310720;           // 16 x 512, rows >= 6 zero
    o_jw[e] = (e < 6 * ND) ? __float2half(jw[e]) : __float2half(0.f);
  }
}

// ---------------------------------------------------------------------------
// fp16 MFMA GEMM, BOTH xg projections in one launch (grid.z selects dir).
// ---------------------------------------------------------------------------
__global__ __launch_bounds__(256) void gemm16_dual(
    const __half* __restrict__ A,
    const __half* __restrict__ B0, const __half* __restrict__ B1,
    fpp bias0, fpp bias1, float* __restrict__ C0, float* __restrict__ C1,
    int N, int K)
{
  const __half* __restrict__ Bm = blockIdx.z ? B1 : B0;
  fpp bias = blockIdx.z ? bias1 : bias0;
  float* __restrict__ C = blockIdx.z ? C1 : C0;

  __shared__ __half As[64 * 40];
  __shared__ __half Bs[64 * 40];
  const int bm = blockIdx.x * 64, bn = blockIdx.y * 64;
  const int tid = threadIdx.x;
  const int wave = tid >> 6, lane = tid & 63;
  const int lm = lane & 15, quad = lane >> 4;
  floatx4 acc[4];
#pragma unroll
  for (int nt = 0; nt < 4; nt++) acc[nt] = (floatx4){0.f, 0.f, 0.f, 0.f};

  const int row = tid >> 2, kc = tid & 3;
  for (int k0 = 0; k0 < K; k0 += 32) {
    __syncthreads();
    *(float4*)&As[row * 40 + kc * 8] =
      *(const float4*)&A[(size_t)(bm + row) * K + k0 + kc * 8];
    *(float4*)&Bs[row * 40 + kc * 8] =
      *(const float4*)&Bm[(size_t)(bn + row) * K + k0 + kc * 8];
    __syncthreads();
    half8 af = *(const half8*)&As[(wave * 16 + lm) * 40 + quad * 8];
#pragma unroll
    for (int nt = 0; nt < 4; nt++) {
      half8 bf = *(const half8*)&Bs[(nt * 16 + lm) * 40 + quad * 8];
      acc[nt] = __builtin_amdgcn_mfma_f32_16x16x32_f16(af, bf, acc[nt], 0, 0, 0);
    }
  }
#pragma unroll
  for (int nt = 0; nt < 4; nt++) {
    int n = bn + nt * 16 + lm;
    float bv = bias[n];
#pragma unroll
    for (int r = 0; r < 4; r++) {
      int m = bm + wave * 16 + quad * 4 + r;
      C[(size_t)m * N + n] = acc[nt][r] + bv;
    }
  }
}

// ---------------------------------------------------------------------------
// PERSISTENT GRU (unchanged from r16): 512 thr, weights pinned in registers,
// double-buffered LDS h-state, seq store hoisted a step.
// ---------------------------------------------------------------------------
__global__ __launch_bounds__(512, 2) void gru_persistent(
    const float* __restrict__ xg_f, const float* __restrict__ xg_b,
    const __half* __restrict__ whh16_f, const __half* __restrict__ whh16_b,
    fpp bhh_f, fpp bhh_b, __half* __restrict__ seq)
{
  const int dir  = blockIdx.x & 1;
  const int tile = blockIdx.x >> 1;
  const int bm   = tile * 16;
  const float* __restrict__ xg = dir ? xg_b : xg_f;
  const __half* __restrict__ Whh = dir ? whh16_b : whh16_f;
  fpp bhh = dir ? bhh_b : bhh_f;
  const int dcol = dir * NH;
  const int tid = threadIdx.x;
  const int wave = tid >> 6, lane = tid & 63;
  const int lm = lane & 15, quad = lane >> 4;
  const int n0 = wave * 32;

  __shared__ __half h16s[2][16 * 264];

  const __half* bp[3][2];
#pragma unroll
  for (int g = 0; g < 3; g++)
#pragma unroll
    for (int c = 0; c < 2; c++)
      bp[g][c] = Whh + (size_t)(g * NH + n0 + c * 16 + lm) * NH + quad * 8;

  floatx4 breg[3][2][6];
#pragma unroll
  for (int g = 0; g < 3; g++)
#pragma unroll
    for (int c = 0; c < 2; c++)
#pragma unroll
      for (int kb = 0; kb < 6; kb++)
        breg[g][c][kb] = *(const floatx4*)(bp[g][c] + kb * 32);
#pragma unroll
  for (int g = 0; g < 3; g++)
#pragma unroll
    for (int c = 0; c < 2; c++)
#pragma unroll
      for (int kb = 0; kb < 6; kb++)
        asm volatile("" : "+v"(breg[g][c][kb]));

  float xr_[2][4], xz_[2][4], xn_[2][4];
  float br_[2], bz_[2], bn_[2];
#pragma unroll
  for (int c = 0; c < 2; c++) {
    int n = n0 + c * 16 + lm;
    br_[c] = bhh[n]; bz_[c] = bhh[NH + n]; bn_[c] = bhh[2 * NH + n];
#pragma unroll
    for (int r = 0; r < 4; r++) {
      int m = bm + quad * 4 + r;
      const float* xp = xg + (size_t)m * NG + n;
      xr_[c][r] = xp[0];
      xz_[c][r] = xp[NH];
      xn_[c][r] = xp[2 * NH];
    }
  }

  float hp[2][4];
#pragma unroll
  for (int c = 0; c < 2; c++)
#pragma unroll
    for (int r = 0; r < 4; r++) hp[c][r] = 0.f;

  const int arow = lm * 264 + quad * 8;
  const int cm = tid >> 5, cpart = tid & 31;

  for (int step = 0; step < NT; step++) {
    const int cur = step & 1, prv = cur ^ 1;
    __half* __restrict__ hCur = h16s[cur];
    const __half* __restrict__ hPrv = h16s[prv];
    floatx4 acc[3][2];

    if (step > 0) {
      {
        const int t_prev = dir ? (NT - step) : (step - 1);
        float4 v = *(const float4*)&hPrv[cm * 264 + cpart * 8];
        *(float4*)&seq[((size_t)(bm + cm) * NT + t_prev) * ND + dcol + cpart * 8] = v;
      }
      half8 b6[3][2], b7[3][2];
#pragma unroll
      for (int g = 0; g < 3; g++)
#pragma unroll
        for (int c = 0; c < 2; c++) {
          b6[g][c] = *(const half8*)(bp[g][c] + 192);
          b7[g][c] = *(const half8*)(bp[g][c] + 224);
        }
      {
        half8 a = *(const half8*)&hPrv[arow];
#pragma unroll
        for (int g = 0; g < 3; g++)
#pragma unroll
          for (int c = 0; c < 2; c++)
            acc[g][c] = __builtin_amdgcn_mfma_f32_16x16x32_f16(
                a, __builtin_bit_cast(half8, breg[g][c][0]),
                (floatx4){0.f, 0.f, 0.f, 0.f}, 0, 0, 0);
      }
#pragma unroll
      for (int kb = 1; kb < 6; kb++) {
        half8 a = *(const half8*)&hPrv[arow + kb * 32];
#pragma unroll
        for (int g = 0; g < 3; g++)
#pragma unroll
          for (int c = 0; c < 2; c++)
            acc[g][c] = __builtin_amdgcn_mfma_f32_16x16x32_f16(
                a, __builtin_bit_cast(half8, breg[g][c][kb]), acc[g][c], 0, 0, 0);
      }
      {
        half8 a = *(const half8*)&hPrv[arow + 192];
#pragma unroll
        for (int g = 0; g < 3; g++)
#pragma unroll
          for (int c = 0; c < 2; c++)
            acc[g][c] = __builtin_amdgcn_mfma_f32_16x16x32_f16(a, b6[g][c], acc[g][c], 0, 0, 0);
      }
      {
        half8 a = *(const half8*)&hPrv[arow + 224];
#pragma unroll
        for (int g = 0; g < 3; g++)
#pragma unroll
          for (int c = 0; c < 2; c++)
            acc[g][c] = __builtin_amdgcn_mfma_f32_16x16x32_f16(a, b7[g][c], acc[g][c], 0, 0, 0);
      }
    } else {
#pragma unroll
      for (int g = 0; g < 3; g++)
#pragma unroll
        for (int c = 0; c < 2; c++) acc[g][c] = (floatx4){0.f, 0.f, 0.f, 0.f};
    }

#pragma unroll
    for (int c = 0; c < 2; c++) {
      int n = n0 + c * 16 + lm;
#pragma unroll
      for (int r = 0; r < 4; r++) {
        int m = quad * 4 + r;
        float rg = fast_sig(xr_[c][r] + acc[0][c][r] + br_[c]);
        float zg = fast_sig(xz_[c][r] + acc[1][c][r] + bz_[c]);
        float nn = fast_tanh(xn_[c][r] + rg * (acc[2][c][r] + bn_[c]));
        float hv = (1.f - zg) * nn + zg * hp[c][r];
        hp[c][r] = hv;
        hCur[m * 264 + n] = __float2half(hv);
      }
    }
    __syncthreads();
  }

  {
    const int t_last = dir ? 0 : (NT - 1);
    const __half* hLast = h16s[(NT - 1) & 1];
    float4 v = *(const float4*)&hLast[cm * 264 + cpart * 8];
    *(float4*)&seq[((size_t)(bm + cm) * NT + t_last) * ND + dcol + cpart * 8] = v;
  }
}

// ---------------------------------------------------------------------------
// Attention scores + gJ via MFMA, M=128/block, 2x2 wave partition (r16).
// ---------------------------------------------------------------------------
__global__ __launch_bounds__(256) void attn_score_mfma(
    const __half* __restrict__ seq, const __half* __restrict__ w116,
    const __half* __restrict__ jw16, fpp b1, fpp W2,
    float* __restrict__ scores, float* __restrict__ gJ)
{
  const int bm = blockIdx.x * 128;
  const int tid = threadIdx.x;
  const int wave = tid >> 6, lane = tid & 63;
  const int lm = lane & 15, quad = lane >> 4;
  const int mh = wave & 1;
  const int nh = wave >> 1;

  __shared__ __half As[128 * 40];
  __shared__ __half Bs[256 * 40];
  __shared__ __half Js[16 * 40];
  __shared__ float partial[2][128];

  floatx4 acc[4][8];
  floatx4 accJ[4];
#pragma unroll
  for (int t = 0; t < 4; t++) {
#pragma unroll
    for (int u = 0; u < 8; u++) acc[t][u] = (floatx4){0.f, 0.f, 0.f, 0.f};
    accJ[t] = (floatx4){0.f, 0.f, 0.f, 0.f};
  }

  for (int k0 = 0; k0 < ND; k0 += 32) {
    __syncthreads();
#pragma unroll
    for (int i = 0; i < 2; i++) {
      int e = tid + i * 256;
      int row = e >> 2, kc = e & 3;
      *(float4*)&As[row * 40 + kc * 8] =
        *(const float4*)&seq[(size_t)(bm + row) * ND + k0 + kc * 8];
    }
#pragma unroll
    for (int i = 0; i < 4; i++) {
      int e = tid + i * 256;
      int row = e >> 2, kc = e & 3;
      *(float4*)&Bs[row * 40 + kc * 8] =
        *(const float4*)&w116[(size_t)row * ND + k0 + kc * 8];
    }
    if (tid < 64) {
      int row = tid >> 2, kc = tid & 3;
      *(float4*)&Js[row * 40 + kc * 8] =
        *(const float4*)&jw16[(size_t)row * ND + k0 + kc * 8];
    }
    __syncthreads();
    half8 a[4];
#pragma unroll
    for (int t = 0; t < 4; t++)
      a[t] = *(const half8*)&As[((mh * 4 + t) * 16 + lm) * 40 + quad * 8];
#pragma unroll
    for (int u = 0; u < 8; u++) {
      half8 bf = *(const half8*)&Bs[((nh * 8 + u) * 16 + lm) * 40 + quad * 8];
#pragma unroll
      for (int t = 0; t < 4; t++)
        acc[t][u] = __builtin_amdgcn_mfma_f32_16x16x32_f16(a[t], bf, acc[t][u], 0, 0, 0);
    }
    if (nh == 1) {
      half8 bj = *(const half8*)&Js[lm * 40 + quad * 8];
#pragma unroll
      for (int t = 0; t < 4; t++)
        accJ[t] = __builtin_amdgcn_mfma_f32_16x16x32_f16(a[t], bj, accJ[t], 0, 0, 0);
    }
  }

  float rs[4][4] = {};
#pragma unroll
  for (int u = 0; u < 8; u++) {
    int n = (nh * 8 + u) * 16 + lm;
    float b1v = b1[n], w2v = W2[n];
#pragma unroll
    for (int t = 0; t < 4; t++)
#pragma unroll
      for (int r = 0; r < 4; r++)
        rs[t][r] += fast_tanh(acc[t][u][r] + b1v) * w2v;
  }
#pragma unroll
  for (int t = 0; t < 4; t++)
#pragma unroll
    for (int r = 0; r < 4; r++) {
      rs[t][r] += __shfl_xor(rs[t][r], 1);
      rs[t][r] += __shfl_xor(rs[t][r], 2);
      rs[t][r] += __shfl_xor(rs[t][r], 4);
      rs[t][r] += __shfl_xor(rs[t][r], 8);
    }
  if (lm == 0) {
#pragma unroll
    for (int t = 0; t < 4; t++)
#pragma unroll
      for (int r = 0; r < 4; r++)
        partial[nh][mh * 64 + t * 16 + quad * 4 + r] = rs[t][r];
  }
  if (nh == 1) {
#pragma unroll
    for (int t = 0; t < 4; t++)
#pragma unroll
      for (int r = 0; r < 4; r++) {
        int row = bm + mh * 64 + t * 16 + quad * 4 + r;
        gJ[(size_t)row * 16 + lm] = accJ[t][r];
      }
  }
  __syncthreads();
  if (tid < 128) scores[bm + tid] = partial[0][tid] + partial[1][tid];
}

// ---------------------------------------------------------------------------
// FUSED softmax + cJ + scalar FK. 256-thr blocks; wave = one batch row b.
// ---------------------------------------------------------------------------
__constant__ float c_lower[6] = {-3.1416f, -1.5708f, -3.1416f, -2.6f, -1.5708f, -1.2f};
__constant__ float c_upper[6] = { 3.1416f,  1.5708f,  3.1416f,  0.1f,  1.5708f,  1.2f};

__global__ __launch_bounds__(256) void attn_post(
    const float* __restrict__ scores_in, const float* __restrict__ gJ,
    fpp jb, float* __restrict__ out)
{
  const int wave = threadIdx.x >> 6;
  const int b = blockIdx.x * 4 + wave;
  const int t = threadIdx.x & 63;    // lanes 0..59 active for FK

  // --- softmax over time (wave-wide) ---
  float v = (t < NT) ? scores_in[(size_t)b * NT + t] : -1e30f;
  float m = v;
#pragma unroll
  for (int off = 32; off >= 1; off >>= 1) m = fmaxf(m, __shfl_xor(m, off));
  float e = (t < NT) ? __expf(v - m) : 0.f;
  float sum = e;
#pragma unroll
  for (int off = 32; off >= 1; off >>= 1) sum += __shfl_xor(sum, off);
  float w = e * fast_rcp(sum);

  // --- stage gJ[b] (60x16) + weights into per-wave LDS ---
  __shared__ float gj[4][NT * 16];
  __shared__ float wl[4][64];
  __shared__ float cj[4][16];
  wl[wave][t] = w;
  const float* gsrc = gJ + (size_t)b * NT * 16;
#pragma unroll
  for (int i = 0; i < 15; i++) gj[wave][t + i * 64] = gsrc[t + i * 64];
  __builtin_amdgcn_s_waitcnt(0);  // wave-local LDS ordering
  __builtin_amdgcn_wave_barrier();

  // --- cJ[j] = sum_t w[t]*gJ[t][j] (lanes 0..15) ---
  if (t < 16) {
    float s = 0.f;
    for (int tt = 0; tt < NT; tt++) s += wl[wave][tt] * gj[wave][tt * 16 + t];
    cj[wave][t] = s;
  }
  __builtin_amdgcn_s_waitcnt(0);
  __builtin_amdgcn_wave_barrier();

  if (t >= NT) return;

  float th[6];
#pragma unroll
  for (int j = 0; j < 6; j++) {
    float jnt = gj[wave][t * 16 + j] + cj[wave][j] + jb[j];
    th[j] = jnt * (c_upper[j] - c_lower[j]) + c_lower[j];
  }

  float c0x = 1.f, c0y = 0.f, c0z = 0.f;
  float c1x = 0.f, c1y = 1.f, c1z = 0.f;
  float c2x = 0.f, c2y = 0.f, c2z = 1.f;
  float px = 0.f, py = 0.f, pz = 0.1f;
  float s, cc, tx_, ty_, tz_, ux_, uy_, uz_;

  // rotZ(th0)
  s = sinf(th[0]); cc = cosf(th[0]);
  tx_ = cc * c0x + s * c1x; ty_ = cc * c0y + s * c1y; tz_ = cc * c0z + s * c1z;
  ux_ = -s * c0x + cc * c1x; uy_ = -s * c0y + cc * c1y; uz_ = -s * c0z + cc * c1z;
  c0x = tx_; c0y = ty_; c0z = tz_; c1x = ux_; c1y = uy_; c1z = uz_;

  float shx = px, shy = py, shz = pz;  // shoulder2
  // rotX(th1)
  s = sinf(th[1]); cc = cosf(th[1]);
  tx_ = cc * c1x + s * c2x; ty_ = cc * c1y + s * c2y; tz_ = cc * c1z + s * c2z;
  ux_ = -s * c1x + cc * c2x; uy_ = -s * c1y + cc * c2y; uz_ = -s * c1z + cc * c2z;
  c1x = tx_; c1y = ty_; c1z = tz_; c2x = ux_; c2y = uy_; c2z = uz_;

  // rotY(th2)
  s = sinf(th[2]); cc = cosf(th[2]);
  tx_ = cc * c0x - s * c2x; ty_ = cc * c0y - s * c2y; tz_ = cc * c0z - s * c2z;
  ux_ = s * c0x + cc * c2x; uy_ = s * c0y + cc * c2y; uz_ = s * c0z + cc * c2z;
  c0x = tx_; c0y = ty_; c0z = tz_; c2x = ux_; c2y = uy_; c2z = uz_;

  // joint3 offset -> forearm
  px -= 0.25f * c1x; py -= 0.25f * c1y; pz -= 0.25f * c1z;
  float fox = px, foy = py, foz = pz;
  // rotX(th3)
  s = sinf(th[3]); cc = cosf(th[3]);
  tx_ = cc * c1x + s * c2x; ty_ = cc * c1y + s * c2y; tz_ = cc * c1z + s * c2z;
  ux_ = -s * c1x + cc * c2x; uy_ = -s * c1y + cc * c2y; uz_ = -s * c1z + cc * c2z;
  c1x = tx_; c1y = ty_; c1z = tz_; c2x = ux_; c2y = uy_; c2z = uz_;

  // rotY(th4)
  s = sinf(th[4]); cc = cosf(th[4]);
  tx_ = cc * c0x - s * c2x; ty_ = cc * c0y - s * c2y; tz_ = cc * c0z - s * c2z;
  ux_ = s * c0x + cc * c2x; uy_ = s * c0y + cc * c2y; uz_ = s * c0z + cc * c2z;
  c0x = tx_; c0y = ty_; c0z = tz_; c2x = ux_; c2y = uy_; c2z = uz_;

  // joint5 offset -> wrist
  px -= 0.25f * c1x; py -= 0.25f * c1y; pz -= 0.25f * c1z;
  float wx = px, wy = py, wz = pz;
  // rotX(th5)
  s = sinf(th[5]); cc = cosf(th[5]);
  tx_ = cc * c1x + s * c2x; ty_ = cc * c1y + s * c2y; tz_ = cc * c1z + s * c2z;
  ux_ = -s * c1x + cc * c2x; uy_ = -s * c1y + cc * c2y; uz_ = -s * c1z + cc * c2z;
  c1x = tx_; c1y = ty_; c1z = tz_; c2x = ux_; c2y = uy_; c2z = uz_;

  float f1x = wx - 0.08f * c1x + 0.02f * c2x;
  float f1y = wy - 0.08f * c1y + 0.02f * c2y;
  float f1z = wz - 0.08f * c1z + 0.02f * c2z;
  float f4x = wx - 0.08f * c1x - 0.02f * c2x;
  float f4y = wy - 0.08f * c1y - 0.02f * c2y;
  float f4z = wz - 0.08f * c1z - 0.02f * c2z;

  float dsx = shx - fox, dsy = shy - foy, dsz = shz - foz;
  float dwx = wx - fox, dwy = wy - foy, dwz = wz - foz;
  float bodyL = 0.5f * (sqrtf(dsx * dsx + dsy * dsy + dsz * dsz) +
                        sqrtf(dwx * dwx + dwy * dwy + dwz * dwz));
  float inv = fast_rcp(bodyL);

  float* o = out + ((size_t)b * NT + t) * 9;
  o[0] = (wx - shx) * inv; o[1] = (wy - shy) * inv; o[2] = (wz - shz) * inv;
  o[3] = (f1x - shx) * inv; o[4] = (f1y - shy) * inv; o[5] = (f1z - shz) * inv;
  o[6] = (f4x - shx) * inv; o[7] = (f4y - shy) * inv; o[8] = (f4z - shz) * inv;
}

// ---------------------------------------------------------------------------
extern "C" void kernel_launch(void* const* d_in, const int* in_sizes, int n_in,
                              void* d_out, int out_size, void* d_ws, size_t ws_size,
                              hipStream_t stream)
{
  fpp z     = (fpp)d_in[0];
  fpp W_fc  = (fpp)d_in[1];
  fpp b_fc  = (fpp)d_in[2];
  fpp bn_g  = (fpp)d_in[3];
  fpp bn_b  = (fpp)d_in[4];
  fpp Wih_f = (fpp)d_in[5];
  fpp Whh_f = (fpp)d_in[6];
  fpp bih_f = (fpp)d_in[7];
  fpp bhh_f = (fpp)d_in[8];
  fpp Wih_b = (fpp)d_in[9];
  fpp Whh_b = (fpp)d_in[10];
  fpp bih_b = (fpp)d_in[11];
  fpp bhh_b = (fpp)d_in[12];
  fpp aW1   = (fpp)d_in[13];
  fpp ab1   = (fpp)d_in[14];
  fpp aW2   = (fpp)d_in[15];
  fpp jW    = (fpp)d_in[16];
  fpp jb    = (fpp)d_in[17];

  float* ws     = (float*)d_ws;
  float* h0     = ws;                        // 2048*512 fp32
  float* xg_f   = h0 + 1048576;              // 2048*768 fp32
  float* xg_b   = xg_f + 1572864;            // 2048*768 fp32
  float* bns1   = xg_b + 1572864;            // 512
  float* bns2   = bns1 + 512;                // 512
  float* scores = bns2 + 512;                // 2048*60
  float* cbuf   = scores + 122880;           // 2048*512 (layout keep)
  __half* gseq    = (__half*)(cbuf + 1048576);   // 2048*60*512 fp16 (126 MB)
  __half* whh16_f = gseq + 62914560;             // 768*256
  __half* whh16_b = whh16_f + 196608;            // 768*256
  __half* w116    = whh16_b + 196608;            // 256*512
  __half* wih16_f = w116 + 131072;               // 768*512
  __half* wih16_b = wih16_f + 393216;            // 768*512
  __half* h16g    = wih16_b + 393216;            // 2048*512
  __half* jw16    = h16g + 1048576;              // 16*512
  float*  gJ      = (float*)(jw16 + 8192);       // 122880*16 fp32 (7.9 MB)

  // 0. weight conversions fp32->fp16 (incl. zero-padded jW) + BN acc zero
  convert_w<<<5152, 256, 0, stream>>>(Whh_f, Whh_b, aW1, Wih_f, Wih_b, jW,
                                      whh16_f, whh16_b, w116, wih16_f, wih16_b,
                                      jw16);
  hipMemsetAsync(bns1, 0, 1024 * sizeof(float), stream);
  // 1. fc + fused BN partial sums
  gemm_fc_bn<<<dim3(32, 8), 256, 0, stream>>>(z, W_fc, b_fc, h0, bns1, bns2,
                                              NB, ND, NDL, NDL, NDL, ND);
  // 2. bn scale/shift + leaky relu -> fp16 h
  bn_lrelu_h16<<<4096, 256, 0, stream>>>(h0, bn_g, bn_b, bns1, bns2, h16g);
  // 3. BOTH time-invariant input projections in one launch
  gemm16_dual<<<dim3(32, 12, 2), 256, 0, stream>>>(
      h16g, wih16_f, wih16_b, bih_f, bih_b, xg_f, xg_b, NG, ND);
  // 4. ENTIRE GRU recurrence: one persistent launch, 8 waves/block
  gru_persistent<<<256, 512, 0, stream>>>(xg_f, xg_b, whh16_f, whh16_b,
                                          bhh_f, bhh_b, gseq);
  // 5. attention scores + gJ (2x2 wave-partitioned MFMA)
  attn_score_mfma<<<960, 256, 0, stream>>>(gseq, w116, jw16, ab1, aW2,
                                           scores, gJ);
  // 6. fused softmax + cJ + FK (4 rows per 256-thr block)
  attn_post<<<512, 256, 0, stream>>>(scores, gJ, jb, (float*)d_out);
}